// Round 12
// baseline (100.439 us; speedup 1.0000x reference)
//
#include <hip/hip_runtime.h>
#include <math.h>

#define BATCH 8192
#define FEAT  256
#define NCLS  1000

#define NGEMM   528                  // upper-tri 32x32 grid of 32x32 tiles
#define NINTRA  NCLS                 // one block per class, 8 waves each
#define ROWCAP  24                   // rows staged in LDS per class (max class ~23)
#define MEMCAP  96                   // hard cap on class size

// ws (f32): [0,528)      per-GEMM-block min   (plain store, unconditional)
//           [528,1528)   per-class intra max  (plain store, unconditional)
// Every slot written every call -> harness 0xAA poison harmless.

// ---------------- intra: one class per block, 8 waves, 512 threads ----------
__global__ __launch_bounds__(512) void k_intra(const float* __restrict__ x,
                                               const int* __restrict__ labels,
                                               float* __restrict__ ws) {
    __shared__ __align__(16) float rowS[ROWCAP][256];   // 24576 B
    __shared__ int   mem[MEMCAP];
    __shared__ float magS[MEMCAP];
    __shared__ float wred[8];
    __shared__ int cnt;
    int t = threadIdx.x;
    int lane = t & 63, w = t >> 6;                      // 8 waves
    int c = blockIdx.x;

    if (t == 0) cnt = 0;
    __syncthreads();
    // find members: coalesced int4 scan of labels (32KB, L2-resident)
    const int4* gl4 = reinterpret_cast<const int4*>(labels);
    #pragma unroll
    for (int k = 0; k < 4; ++k) {
        int idx = t + (k << 9);
        int4 lv = gl4[idx];
        int base = idx << 2;
        if (lv.x == c) { int p = atomicAdd(&cnt, 1); if (p < MEMCAP) mem[p] = base;     }
        if (lv.y == c) { int p = atomicAdd(&cnt, 1); if (p < MEMCAP) mem[p] = base + 1; }
        if (lv.z == c) { int p = atomicAdd(&cnt, 1); if (p < MEMCAP) mem[p] = base + 2; }
        if (lv.w == c) { int p = atomicAdd(&cnt, 1); if (p < MEMCAP) mem[p] = base + 3; }
    }
    __syncthreads();
    int n = cnt < MEMCAP ? cnt : MEMCAP;
    float vmax = 0.0f;
    if (n >= 2) {
        const float4* x4 = reinterpret_cast<const float4*>(x);
        // stage rows + tree mags: 8 waves -> 8 rows in flight block-wide
        for (int m = w; m < n; m += 8) {
            float4 v = x4[(size_t)mem[m] * 64 + lane];
            if (m < ROWCAP)
                *reinterpret_cast<float4*>(&rowS[m][lane << 2]) = v;
            float s = v.x * v.x + v.y * v.y + v.z * v.z + v.w * v.w;
            #pragma unroll
            for (int o = 32; o > 0; o >>= 1) s += __shfl_xor(s, o);   // bit-exact tree
            if (lane == 0) magS[m] = s;
        }
        __syncthreads();
        int npairs = n * (n - 1) / 2;
        // two pairs per iteration (independent chains, named scalars only)
        for (int p = w; p < npairs; p += 16) {
            int p2 = p + 8;
            bool has2 = (p2 < npairs);
            int a1 = 0, r1 = p;                          // unrank (a-major)
            while (r1 >= n - 1 - a1) { r1 -= n - 1 - a1; ++a1; }
            int b1 = a1 + 1 + r1;
            int a2 = a1, b2 = b1;
            if (has2) {
                int r2 = p2; a2 = 0;
                while (r2 >= n - 1 - a2) { r2 -= n - 1 - a2; ++a2; }
                b2 = a2 + 1 + r2;
            }
            float4 va1 = (a1 < ROWCAP) ? *reinterpret_cast<float4*>(&rowS[a1][lane << 2])
                                       : x4[(size_t)mem[a1] * 64 + lane];
            float4 vb1 = (b1 < ROWCAP) ? *reinterpret_cast<float4*>(&rowS[b1][lane << 2])
                                       : x4[(size_t)mem[b1] * 64 + lane];
            float4 va2 = (a2 < ROWCAP) ? *reinterpret_cast<float4*>(&rowS[a2][lane << 2])
                                       : x4[(size_t)mem[a2] * 64 + lane];
            float4 vb2 = (b2 < ROWCAP) ? *reinterpret_cast<float4*>(&rowS[b2][lane << 2])
                                       : x4[(size_t)mem[b2] * 64 + lane];
            float s1 = va1.x * vb1.x + va1.y * vb1.y + va1.z * vb1.z + va1.w * vb1.w;
            float s2 = va2.x * vb2.x + va2.y * vb2.y + va2.z * vb2.z + va2.w * vb2.w;
            #pragma unroll
            for (int o = 32; o > 0; o >>= 1) {           // interleaved independent trees
                s1 += __shfl_xor(s1, o);
                s2 += __shfl_xor(s2, o);
            }
            float d2a = magS[a1] + magS[b1] - 2.0f * s1; // add commutes: bit-same
            float da  = sqrtf(fmaxf(d2a, 0.0f));
            da = fminf(fmaxf(da, 1e-12f), 1e12f);
            vmax = fmaxf(vmax, da);
            if (has2) {
                float d2b = magS[a2] + magS[b2] - 2.0f * s2;
                float db  = sqrtf(fmaxf(d2b, 0.0f));
                db = fminf(fmaxf(db, 1e-12f), 1e12f);
                vmax = fmaxf(vmax, db);
            }
        }
    }
    if (lane == 0) wred[w] = vmax;
    __syncthreads();
    if (t == 0) {
        float m = 0.0f;
        #pragma unroll
        for (int q = 0; q < 8; ++q) m = fmaxf(m, wred[q]);
        ws[NGEMM + c] = m;                               // plain store, unique slot
    }
}

// ------- inter: upper-tri 32x32 tile, k-major LDS, 2x2 reg tile (R11-exact) ----
__global__ __launch_bounds__(256) void k_inter(const float* __restrict__ centers,
                                               float* __restrict__ ws) {
    __shared__ float As[32][34];
    __shared__ float Bs[32][34];
    __shared__ float cmagI[32], cmagJ[32];
    __shared__ float wred[4];
    int t = threadIdx.x;
    int lane = t & 63, w = t >> 6;

    int bi = 0, rem = blockIdx.x;               // unrank upper-tri 32x32 grid
    while (rem >= 32 - bi) { rem -= 32 - bi; ++bi; }
    int bj = bi + rem;
    int i0 = bi * 32, j0 = bj * 32;

    // cmag for both row-ranges (bit-exact rownorm tree, I/J interleaved)
    for (int q = w; q < 32; q += 4) {
        int gi = i0 + q, gj = j0 + q;
        float sI = 0.0f, sJ = 0.0f;
        if (gi < NCLS) {
            float4 v = reinterpret_cast<const float4*>(centers + (size_t)gi * FEAT)[lane];
            sI = v.x * v.x + v.y * v.y + v.z * v.z + v.w * v.w;
        }
        if (gj < NCLS) {
            float4 v = reinterpret_cast<const float4*>(centers + (size_t)gj * FEAT)[lane];
            sJ = v.x * v.x + v.y * v.y + v.z * v.z + v.w * v.w;
        }
        #pragma unroll
        for (int o = 32; o > 0; o >>= 1) {
            sI += __shfl_xor(sI, o);
            sJ += __shfl_xor(sJ, o);
        }
        if (lane == 0) { cmagI[q] = 2.0f * sI; cmagJ[q] = 2.0f * sJ; }
    }
    // (k-loop barriers below order cmag writes before the epilogue reads)

    int tx = t & 15, ty = t >> 4;               // 2 cols, 2 rows per thread
    float acc[2][2] = {{0.f, 0.f}, {0.f, 0.f}};
    for (int kk = 0; kk < FEAT; kk += 32) {
        {   // stage 32 rows x 32 k, k-major (2-way write alias = free)
            int row = t >> 3, q = t & 7;
            int col = kk + q * 4;
            int gi = i0 + row, gj = j0 + row;
            float4 av = (gi < NCLS)
                ? *reinterpret_cast<const float4*>(centers + (size_t)gi * FEAT + col)
                : make_float4(0.f, 0.f, 0.f, 0.f);
            float4 bv = (gj < NCLS)
                ? *reinterpret_cast<const float4*>(centers + (size_t)gj * FEAT + col)
                : make_float4(0.f, 0.f, 0.f, 0.f);
            As[q * 4 + 0][row] = av.x; As[q * 4 + 1][row] = av.y;
            As[q * 4 + 2][row] = av.z; As[q * 4 + 3][row] = av.w;
            Bs[q * 4 + 0][row] = bv.x; Bs[q * 4 + 1][row] = bv.y;
            Bs[q * 4 + 2][row] = bv.z; Bs[q * 4 + 3][row] = bv.w;
        }
        __syncthreads();
        #pragma unroll
        for (int k = 0; k < 32; ++k) {          // k strictly sequential per acc
            float2 a2 = *reinterpret_cast<float2*>(&As[k][ty * 2]);
            float2 b2 = *reinterpret_cast<float2*>(&Bs[k][tx * 2]);
            acc[0][0] += a2.x * b2.x; acc[0][1] += a2.x * b2.y;
            acc[1][0] += a2.y * b2.x; acc[1][1] += a2.y * b2.y;
        }
        __syncthreads();
    }
    float lmin = 1e30f;
    #pragma unroll
    for (int jj = 0; jj < 2; ++jj) {
        int J = j0 + tx * 2 + jj;
        #pragma unroll
        for (int ii = 0; ii < 2; ++ii) {
            int I = i0 + ty * 2 + ii;
            if (I < NCLS && J < NCLS) {
                float v1 = cmagJ[tx * 2 + jj] - 2.0f * acc[ii][jj];   // entry (I,J)
                v1 = fminf(fmaxf(v1, 1e-12f), 1e12f);
                float v2 = cmagI[ty * 2 + ii] - 2.0f * acc[ii][jj];   // entry (J,I)
                v2 = fminf(fmaxf(v2, 1e-12f), 1e12f);
                lmin = fminf(lmin, fminf(v1, v2));
            }
        }
    }
    #pragma unroll
    for (int o = 32; o > 0; o >>= 1) lmin = fminf(lmin, __shfl_xor(lmin, o));
    if (lane == 0) wred[w] = lmin;
    __syncthreads();
    if (t == 0) {
        float m = fminf(fminf(wred[0], wred[1]), fminf(wred[2], wred[3]));
        ws[blockIdx.x] = m;                         // plain store, unique slot
    }
}

// One block, 256 threads: reduce the per-block partials, write the scalar.
__global__ __launch_bounds__(256) void k_final(const float* __restrict__ ws,
                                               float* __restrict__ out) {
    __shared__ float smx[4], smn[4];
    int t = threadIdx.x, lane = t & 63, w = t >> 6;
    float mn = 1e30f, mx = 0.0f;
    for (int i = t; i < NGEMM; i += 256)  mn = fminf(mn, ws[i]);
    for (int i = t; i < NINTRA; i += 256) mx = fmaxf(mx, ws[NGEMM + i]);
    #pragma unroll
    for (int o = 32; o > 0; o >>= 1) {
        mx = fmaxf(mx, __shfl_xor(mx, o));
        mn = fminf(mn, __shfl_xor(mn, o));
    }
    if (lane == 0) { smx[w] = mx; smn[w] = mn; }
    __syncthreads();
    if (t == 0) {
        mx = fmaxf(fmaxf(smx[0], smx[1]), fmaxf(smx[2], smx[3]));
        mn = fminf(fminf(smn[0], smn[1]), fminf(smn[2], smn[3]));
        float M = fmaxf(mx, 1e-12f);                  // diagonal clamp floor
        float r = 1.0f / M;
        float li2 = 2.0f / (r + r);                   // harmonic mean of [M,M] * 2
        float m = fminf(mn, 1e12f);
        float linter = fminf(fmaxf(5.0f - m, 0.0f), 1e6f);
        out[0] = li2 + linter;                        // ALPHA = BETA = 1
    }
}

extern "C" void kernel_launch(void* const* d_in, const int* in_sizes, int n_in,
                              void* d_out, int out_size, void* d_ws, size_t ws_size,
                              hipStream_t stream) {
    const float* x       = (const float*)d_in[0];
    const int*   labels  = (const int*)d_in[1];
    const float* centers = (const float*)d_in[2];
    float*        ws     = (float*)d_ws;
    float*        out    = (float*)d_out;

    k_intra<<<NINTRA, 512, 0, stream>>>(x, labels, ws);
    k_inter<<<NGEMM, 256, 0, stream>>>(centers, ws);
    k_final<<<1, 256, 0, stream>>>(ws, out);
}

// Round 13
// 92.768 us; speedup vs baseline: 1.0827x; 1.0827x over previous
//
#include <hip/hip_runtime.h>
#include <math.h>

#define BATCH 8192
#define FEAT  256
#define NCLS  1000

#define NGEMM  528                   // upper-tri 32x32 grid of 32x32 tiles, FIRST
#define REPL   4                     // pair-replica blocks per class
#define NPAIRB (REPL*NCLS)           // 4000
#define NBLK   (NGEMM + NPAIRB)      // 4528
#define SLOTC  64                    // per-class member capacity (max class ~23)

// ws byte layout (counts memset to 0 each call; everything else fully
// overwritten before it is read -> harness 0xAA poison harmless):
//   [0,      4000)    counts[1000]  int
//   [4096,   260096)  mem[1000][64] int   (member row ids per class)
//   [262144, 294912)  mag[8192]     float (bit-exact tree row norms)
//   [294912, 313024)  part[4528]    float (per-block partials)

// ---- prep: one wave per row: mag + scatter into per-class member table ----
__global__ __launch_bounds__(256) void k_prep(const float* __restrict__ x,
                                              const int* __restrict__ labels,
                                              int* __restrict__ counts,
                                              int* __restrict__ mem,
                                              float* __restrict__ mag) {
    int gw   = (blockIdx.x * 256 + threadIdx.x) >> 6;    // row id, 0..8191
    int lane = threadIdx.x & 63;
    float4 v = reinterpret_cast<const float4*>(x)[(size_t)gw * 64 + lane];
    float s = v.x * v.x + v.y * v.y + v.z * v.z + v.w * v.w;
    #pragma unroll
    for (int o = 32; o > 0; o >>= 1) s += __shfl_xor(s, o);   // bit-exact tree
    if (lane == 0) {
        mag[gw] = s;
        int c = labels[gw];
        int pos = atomicAdd(&counts[c], 1);                   // 1000 distinct cells
        if (pos < SLOTC) mem[c * SLOTC + pos] = gw;
    }
}

// ---- fused: [0,528) = inter GEMM tiles (R11-exact); [528,4528) = pair blocks ----
__global__ __launch_bounds__(256) void k_fused(const float* __restrict__ x,
                                               const float* __restrict__ centers,
                                               const int* __restrict__ counts,
                                               const int* __restrict__ mem,
                                               const float* __restrict__ mag,
                                               float* __restrict__ part) {
    __shared__ float As[32][34];
    __shared__ float Bs[32][34];
    __shared__ float cmagI[32], cmagJ[32];
    __shared__ float wred[4];
    int t = threadIdx.x;
    int lane = t & 63, w = t >> 6;

    if (blockIdx.x < NGEMM) {
        // ------- inter: upper-tri 32x32 tile, k-major LDS, 2x2 reg tile -------
        int bi = 0, rem = blockIdx.x;               // unrank upper-tri 32x32 grid
        while (rem >= 32 - bi) { rem -= 32 - bi; ++bi; }
        int bj = bi + rem;
        int i0 = bi * 32, j0 = bj * 32;

        // cmag for both row-ranges (bit-exact rownorm tree, I/J interleaved)
        for (int q = w; q < 32; q += 4) {
            int gi = i0 + q, gj = j0 + q;
            float sI = 0.0f, sJ = 0.0f;
            if (gi < NCLS) {
                float4 v = reinterpret_cast<const float4*>(centers + (size_t)gi * FEAT)[lane];
                sI = v.x * v.x + v.y * v.y + v.z * v.z + v.w * v.w;
            }
            if (gj < NCLS) {
                float4 v = reinterpret_cast<const float4*>(centers + (size_t)gj * FEAT)[lane];
                sJ = v.x * v.x + v.y * v.y + v.z * v.z + v.w * v.w;
            }
            #pragma unroll
            for (int o = 32; o > 0; o >>= 1) {
                sI += __shfl_xor(sI, o);
                sJ += __shfl_xor(sJ, o);
            }
            if (lane == 0) { cmagI[q] = 2.0f * sI; cmagJ[q] = 2.0f * sJ; }
        }
        // (k-loop barriers below order cmag writes before the epilogue reads)

        int tx = t & 15, ty = t >> 4;               // 2 cols, 2 rows per thread
        float acc[2][2] = {{0.f, 0.f}, {0.f, 0.f}};
        for (int kk = 0; kk < FEAT; kk += 32) {
            {   // stage 32 rows x 32 k, k-major (2-way write alias = free)
                int row = t >> 3, q = t & 7;
                int col = kk + q * 4;
                int gi = i0 + row, gj = j0 + row;
                float4 av = (gi < NCLS)
                    ? *reinterpret_cast<const float4*>(centers + (size_t)gi * FEAT + col)
                    : make_float4(0.f, 0.f, 0.f, 0.f);
                float4 bv = (gj < NCLS)
                    ? *reinterpret_cast<const float4*>(centers + (size_t)gj * FEAT + col)
                    : make_float4(0.f, 0.f, 0.f, 0.f);
                As[q * 4 + 0][row] = av.x; As[q * 4 + 1][row] = av.y;
                As[q * 4 + 2][row] = av.z; As[q * 4 + 3][row] = av.w;
                Bs[q * 4 + 0][row] = bv.x; Bs[q * 4 + 1][row] = bv.y;
                Bs[q * 4 + 2][row] = bv.z; Bs[q * 4 + 3][row] = bv.w;
            }
            __syncthreads();
            #pragma unroll
            for (int k = 0; k < 32; ++k) {          // k strictly sequential per acc
                float2 a2 = *reinterpret_cast<float2*>(&As[k][ty * 2]);
                float2 b2 = *reinterpret_cast<float2*>(&Bs[k][tx * 2]);
                acc[0][0] += a2.x * b2.x; acc[0][1] += a2.x * b2.y;
                acc[1][0] += a2.y * b2.x; acc[1][1] += a2.y * b2.y;
            }
            __syncthreads();
        }
        float lmin = 1e30f;
        #pragma unroll
        for (int jj = 0; jj < 2; ++jj) {
            int J = j0 + tx * 2 + jj;
            #pragma unroll
            for (int ii = 0; ii < 2; ++ii) {
                int I = i0 + ty * 2 + ii;
                if (I < NCLS && J < NCLS) {
                    float v1 = cmagJ[tx * 2 + jj] - 2.0f * acc[ii][jj];   // entry (I,J)
                    v1 = fminf(fmaxf(v1, 1e-12f), 1e12f);
                    float v2 = cmagI[ty * 2 + ii] - 2.0f * acc[ii][jj];   // entry (J,I)
                    v2 = fminf(fmaxf(v2, 1e-12f), 1e12f);
                    lmin = fminf(lmin, fminf(v1, v2));
                }
            }
        }
        #pragma unroll
        for (int o = 32; o > 0; o >>= 1) lmin = fminf(lmin, __shfl_xor(lmin, o));
        if (lane == 0) wred[w] = lmin;
        __syncthreads();
        if (t == 0) {
            float m = fminf(fminf(wred[0], wred[1]), fminf(wred[2], wred[3]));
            part[blockIdx.x] = m;                       // plain store, unique slot
        }
    } else {
        // ------- intra pairs: no scan, no staging, no barriers in the loop -------
        int bidp = blockIdx.x - NGEMM;
        int c = bidp >> 2, r = bidp & 3;                // class, replica
        int n = counts[c]; if (n > SLOTC) n = SLOTC;
        float vmax = 0.0f;
        if (n >= 2) {
            const float4* x4 = reinterpret_cast<const float4*>(x);
            const int* memc = mem + c * SLOTC;
            int npairs = n * (n - 1) / 2;
            // residues r*4+w and r*4+w+16 (mod 32): 2 pairs in flight, named scalars
            for (int p = r * 4 + w; p < npairs; p += 32) {
                int p2 = p + 16;
                bool has2 = (p2 < npairs);
                int a1 = 0, r1 = p;                      // unrank (a-major)
                while (r1 >= n - 1 - a1) { r1 -= n - 1 - a1; ++a1; }
                int b1 = a1 + 1 + r1;
                int a2 = a1, b2 = b1;
                if (has2) {
                    int r2 = p2; a2 = 0;
                    while (r2 >= n - 1 - a2) { r2 -= n - 1 - a2; ++a2; }
                    b2 = a2 + 1 + r2;
                }
                int ia1 = memc[a1], ib1 = memc[b1];
                int ia2 = memc[a2], ib2 = memc[b2];
                float4 va1 = x4[(size_t)ia1 * 64 + lane];   // 4 independent loads
                float4 vb1 = x4[(size_t)ib1 * 64 + lane];
                float4 va2 = x4[(size_t)ia2 * 64 + lane];
                float4 vb2 = x4[(size_t)ib2 * 64 + lane];
                float s1 = va1.x * vb1.x + va1.y * vb1.y + va1.z * vb1.z + va1.w * vb1.w;
                float s2 = va2.x * vb2.x + va2.y * vb2.y + va2.z * vb2.z + va2.w * vb2.w;
                #pragma unroll
                for (int o = 32; o > 0; o >>= 1) {       // interleaved independent trees
                    s1 += __shfl_xor(s1, o);
                    s2 += __shfl_xor(s2, o);
                }
                float d2a = mag[ia1] + mag[ib1] - 2.0f * s1;   // add commutes: bit-same
                float da  = sqrtf(fmaxf(d2a, 0.0f));
                da = fminf(fmaxf(da, 1e-12f), 1e12f);
                vmax = fmaxf(vmax, da);
                if (has2) {
                    float d2b = mag[ia2] + mag[ib2] - 2.0f * s2;
                    float db  = sqrtf(fmaxf(d2b, 0.0f));
                    db = fminf(fmaxf(db, 1e-12f), 1e12f);
                    vmax = fmaxf(vmax, db);
                }
            }
        }
        if (lane == 0) wred[w] = vmax;
        __syncthreads();
        if (t == 0) {
            float m = fmaxf(fmaxf(wred[0], wred[1]), fmaxf(wred[2], wred[3]));
            part[blockIdx.x] = m;                       // plain store, unique slot
        }
    }
}

// One block, 256 threads: reduce the per-block partials, write the scalar.
__global__ __launch_bounds__(256) void k_final(const float* __restrict__ part,
                                               float* __restrict__ out) {
    __shared__ float smx[4], smn[4];
    int t = threadIdx.x, lane = t & 63, w = t >> 6;
    float mn = 1e30f, mx = 0.0f;
    for (int i = t; i < NGEMM; i += 256)  mn = fminf(mn, part[i]);
    for (int i = t; i < NPAIRB; i += 256) mx = fmaxf(mx, part[NGEMM + i]);
    #pragma unroll
    for (int o = 32; o > 0; o >>= 1) {
        mx = fmaxf(mx, __shfl_xor(mx, o));
        mn = fminf(mn, __shfl_xor(mn, o));
    }
    if (lane == 0) { smx[w] = mx; smn[w] = mn; }
    __syncthreads();
    if (t == 0) {
        mx = fmaxf(fmaxf(smx[0], smx[1]), fmaxf(smx[2], smx[3]));
        mn = fminf(fminf(smn[0], smn[1]), fminf(smn[2], smn[3]));
        float M = fmaxf(mx, 1e-12f);                  // diagonal clamp floor
        float r = 1.0f / M;
        float li2 = 2.0f / (r + r);                   // harmonic mean of [M,M] * 2
        float m = fminf(mn, 1e12f);
        float linter = fminf(fmaxf(5.0f - m, 0.0f), 1e6f);
        out[0] = li2 + linter;                        // ALPHA = BETA = 1
    }
}

extern "C" void kernel_launch(void* const* d_in, const int* in_sizes, int n_in,
                              void* d_out, int out_size, void* d_ws, size_t ws_size,
                              hipStream_t stream) {
    const float* x       = (const float*)d_in[0];
    const int*   labels  = (const int*)d_in[1];
    const float* centers = (const float*)d_in[2];
    char* wsb = (char*)d_ws;
    int*   counts = (int*)(wsb);
    int*   mem    = (int*)(wsb + 4096);
    float* mag    = (float*)(wsb + 262144);
    float* part   = (float*)(wsb + 294912);
    float* out    = (float*)d_out;

    hipMemsetAsync(counts, 0, NCLS * sizeof(int), stream);
    k_prep<<<BATCH / 4, 256, 0, stream>>>(x, labels, counts, mem, mag);
    k_fused<<<NBLK, 256, 0, stream>>>(x, centers, counts, mem, mag, part);
    k_final<<<1, 256, 0, stream>>>(part, out);
}